// Round 1
// baseline (132.791 us; speedup 1.0000x reference)
//
#include <hip/hip_runtime.h>

#define B 4096
#define D 128
#define TI 64
#define TJ 64
#define NCB 8               // column groups (blockIdx.y)
#define NCHUNK ((B / NCB) / TJ)   // 8 chunks of 64 cols per block

// ws layout (floats): sq[0..4096) | num[4096..8192) | den[8192..12288)

__global__ __launch_bounds__(256) void prep_kernel(const float* __restrict__ x,
        float* __restrict__ sq, float* __restrict__ num, float* __restrict__ den,
        float* __restrict__ out) {
    int tid = threadIdx.x;
    int row = blockIdx.x * 8 + (tid >> 5);   // 32 threads per row
    int lane = tid & 31;
    const float4* xg = (const float4*)x;
    float4 v = xg[row * 32 + lane];
    float s = v.x * v.x + v.y * v.y + v.z * v.z + v.w * v.w;
    #pragma unroll
    for (int off = 16; off > 0; off >>= 1) s += __shfl_down(s, off);
    if (lane == 0) sq[row] = s;
    int gid = blockIdx.x * 256 + tid;
    if (gid < B) { num[gid] = 0.f; den[gid] = 0.f; }
    if (gid == 0) out[0] = 0.f;
}

__global__ __launch_bounds__(256) void snn_main(const float* __restrict__ x,
        const int* __restrict__ y, const float* __restrict__ sqg,
        float* __restrict__ num, float* __restrict__ den) {
    // row stride 33 float4s (132 floats) -> rows spread across LDS bank groups
    __shared__ float4 xiS[TI * 33];
    __shared__ float4 xjS[TJ * 33];
    __shared__ float redn[TI][16];
    __shared__ float redd[TI][16];

    const int tid = threadIdx.x;
    const int ti = tid >> 4;   // 0..15, row-thread
    const int tj = tid & 15;   // 0..15, col-thread
    const int i0 = blockIdx.x * TI;
    const int jbase = blockIdx.y * (B / NCB);

    const float4* xg = (const float4*)x;

    // stage A-tile (64 rows x 128 floats), coalesced float4
    {
        int f = tid;
        #pragma unroll
        for (int r = 0; r < 8; ++r, f += 256) {
            int row = f >> 5, c = f & 31;
            xiS[row * 33 + c] = xg[(i0 + row) * 32 + c];
        }
    }

    // per-thread row metadata (strided micro-tile: rows ti+16a)
    float sqi_r[4]; int yi_r[4]; int irow[4];
    #pragma unroll
    for (int a = 0; a < 4; ++a) {
        irow[a] = i0 + ti + 16 * a;
        sqi_r[a] = sqg[irow[a]];
        yi_r[a] = y[irow[a]];
    }

    float numa[4] = {0.f, 0.f, 0.f, 0.f};
    float dena[4] = {0.f, 0.f, 0.f, 0.f};

    for (int cch = 0; cch < NCHUNK; ++cch) {
        int j0 = jbase + cch * TJ;
        if (cch > 0) __syncthreads();   // previous chunk's reads done before overwrite
        int f = tid;
        #pragma unroll
        for (int r = 0; r < 8; ++r, f += 256) {
            int row = f >> 5, c = f & 31;
            xjS[row * 33 + c] = xg[(j0 + row) * 32 + c];
        }
        __syncthreads();

        float acc[4][4];
        #pragma unroll
        for (int a = 0; a < 4; ++a)
            #pragma unroll
            for (int b = 0; b < 4; ++b) acc[a][b] = 0.f;

        for (int k4 = 0; k4 < 32; ++k4) {
            float4 av[4], bv[4];
            #pragma unroll
            for (int a = 0; a < 4; ++a) av[a] = xiS[(ti + 16 * a) * 33 + k4];
            #pragma unroll
            for (int b = 0; b < 4; ++b) bv[b] = xjS[(tj + 16 * b) * 33 + k4];
            #pragma unroll
            for (int a = 0; a < 4; ++a)
                #pragma unroll
                for (int b = 0; b < 4; ++b)
                    acc[a][b] += av[a].x * bv[b].x + av[a].y * bv[b].y
                               + av[a].z * bv[b].z + av[a].w * bv[b].w;
        }

        // epilogue for this 64-col chunk
        #pragma unroll
        for (int bq = 0; bq < 4; ++bq) {
            int j = j0 + tj + 16 * bq;
            float sqj = sqg[j];
            int yj = y[j];
            #pragma unroll
            for (int a = 0; a < 4; ++a) {
                float dist = fmaxf(sqi_r[a] + sqj - 2.f * acc[a][bq], 0.f);
                float e = __expf(-dist * 0.01f);   // 1/T, T=100
                dena[a] += e;
                if ((yi_r[a] == yj) && (irow[a] != j)) numa[a] += e;
            }
        }
    }

    // block-level reduction over the 16 col-threads, then one atomic per row
    #pragma unroll
    for (int a = 0; a < 4; ++a) {
        redn[ti + 16 * a][tj] = numa[a];
        redd[ti + 16 * a][tj] = dena[a];
    }
    __syncthreads();
    if (tid < TI) {
        float sn = 0.f, sd = 0.f;
        #pragma unroll
        for (int t = 0; t < 16; ++t) { sn += redn[tid][t]; sd += redd[tid][t]; }
        atomicAdd(&num[i0 + tid], sn);
        atomicAdd(&den[i0 + tid], sd);
    }
}

__global__ __launch_bounds__(256) void snn_final(const float* __restrict__ num,
        const float* __restrict__ den, float* __restrict__ out) {
    __shared__ float wsum[4];
    int i = blockIdx.x * 256 + threadIdx.x;
    float l = -__logf(num[i] / den[i]);
    #pragma unroll
    for (int off = 32; off > 0; off >>= 1) l += __shfl_down(l, off);
    int wid = threadIdx.x >> 6;
    if ((threadIdx.x & 63) == 0) wsum[wid] = l;
    __syncthreads();
    if (threadIdx.x == 0) {
        float s = wsum[0] + wsum[1] + wsum[2] + wsum[3];
        atomicAdd(out, s * (1.0f / B));
    }
}

extern "C" void kernel_launch(void* const* d_in, const int* in_sizes, int n_in,
                              void* d_out, int out_size, void* d_ws, size_t ws_size,
                              hipStream_t stream) {
    const float* x = (const float*)d_in[0];
    const int*   y = (const int*)d_in[1];
    float* out = (float*)d_out;
    float* sq  = (float*)d_ws;
    float* num = sq + B;
    float* den = num + B;

    prep_kernel<<<B / 8, 256, 0, stream>>>(x, sq, num, den, out);
    dim3 grid(B / TI, NCB);
    snn_main<<<grid, 256, 0, stream>>>(x, y, sq, num, den);
    snn_final<<<B / 256, 256, 0, stream>>>(num, den, out);
}

// Round 2
// 71.203 us; speedup vs baseline: 1.8650x; 1.8650x over previous
//
#include <hip/hip_runtime.h>
#include <hip/hip_bf16.h>

#define NB 4096
#define DD 128

typedef short v8s __attribute__((ext_vector_type(8)));
typedef float v4f __attribute__((ext_vector_type(4)));

// ws layout (bytes): sq[4096]f32 | num[4096]f32 | den[4096]f32 | xb[4096*128]bf16

__global__ __launch_bounds__(256) void prep_kernel(const float* __restrict__ x,
        float* __restrict__ sq, float* __restrict__ num, float* __restrict__ den,
        float* __restrict__ out, unsigned short* __restrict__ xb) {
    int tid = threadIdx.x;
    int row = blockIdx.x * 8 + (tid >> 5);   // 32 threads per row
    int lane = tid & 31;
    const float4* xg = (const float4*)x;
    float4 v = xg[row * 32 + lane];
    // bf16 copy (RNE)
    __hip_bfloat16 h0 = __float2bfloat16(v.x), h1 = __float2bfloat16(v.y);
    __hip_bfloat16 h2 = __float2bfloat16(v.z), h3 = __float2bfloat16(v.w);
    ushort4 u4;
    u4.x = *(unsigned short*)&h0; u4.y = *(unsigned short*)&h1;
    u4.z = *(unsigned short*)&h2; u4.w = *(unsigned short*)&h3;
    ((ushort4*)xb)[row * 32 + lane] = u4;
    // row squared norm (fp32 exact)
    float s = v.x * v.x + v.y * v.y + v.z * v.z + v.w * v.w;
    #pragma unroll
    for (int off = 16; off > 0; off >>= 1) s += __shfl_down(s, off);
    if (lane == 0) sq[row] = s;
    int gid = blockIdx.x * 256 + tid;
    if (gid < NB) { num[gid] = 0.f; den[gid] = 0.f; }
    if (gid == 0) out[0] = 0.f;
}

// 128x128 Gram tile per block via bf16 MFMA, fused SNN epilogue.
__global__ __launch_bounds__(256) void snn_mfma(const unsigned short* __restrict__ xb,
        const int* __restrict__ y, const float* __restrict__ sqg,
        float* __restrict__ num, float* __restrict__ den) {
    // LDS: A/B tiles with padded stride 136 bf16 (68 dwords) -> conflict-free
    // ds_read_b128 fragment loads (bank = 4*((lr+q)&7)+j, 8 dwords/bank).
    // part[] reuses the same LDS after the MFMA phase.
    __shared__ __align__(16) union {
        unsigned short tiles[2 * 128 * 136];   // 69632 B
        float part[2 * 128 * 34];              // 34816 B  [wn][row][17 float2]
    } sm;
    __shared__ float sqi[128], sqj[128];
    __shared__ int yi[128], yj[128];

    const int tid = threadIdx.x;
    const int wave = tid >> 6;
    const int lane = tid & 63;
    const int wm = wave >> 1;      // 0..1 : 64-row half
    const int wn = wave & 1;       // 0..1 : 64-col half
    const int lr = lane & 15;
    const int q  = lane >> 4;      // 0..3
    const int i0 = blockIdx.x * 128;
    const int j0 = blockIdx.y * 128;

    const v8s* xg = (const v8s*)xb;   // 16 chunks of 8 bf16 per row
    unsigned short* At = sm.tiles;
    unsigned short* Bt = sm.tiles + 128 * 136;

    // stage A and B tiles (coalesced 16B chunks)
    #pragma unroll
    for (int r = 0; r < 8; ++r) {
        int c = r * 256 + tid;
        int row = c >> 4, cc = c & 15;
        *(v8s*)&At[row * 136 + cc * 8] = xg[(i0 + row) * 16 + cc];
        *(v8s*)&Bt[row * 136 + cc * 8] = xg[(j0 + row) * 16 + cc];
    }
    if (tid < 128) {
        sqi[tid] = sqg[i0 + tid]; sqj[tid] = sqg[j0 + tid];
        yi[tid] = y[i0 + tid];    yj[tid] = y[j0 + tid];
    }
    __syncthreads();

    v4f acc[4][4];
    #pragma unroll
    for (int mt = 0; mt < 4; ++mt)
        #pragma unroll
        for (int nt = 0; nt < 4; ++nt)
            #pragma unroll
            for (int r = 0; r < 4; ++r) acc[mt][nt][r] = 0.f;

    #pragma unroll
    for (int kk = 0; kk < 4; ++kk) {          // K = 4 x 32
        v8s af[4], bf[4];
        #pragma unroll
        for (int mt = 0; mt < 4; ++mt)
            af[mt] = *(const v8s*)&At[(wm * 64 + mt * 16 + lr) * 136 + kk * 32 + q * 8];
        #pragma unroll
        for (int nt = 0; nt < 4; ++nt)
            bf[nt] = *(const v8s*)&Bt[(wn * 64 + nt * 16 + lr) * 136 + kk * 32 + q * 8];
        #pragma unroll
        for (int mt = 0; mt < 4; ++mt)
            #pragma unroll
            for (int nt = 0; nt < 4; ++nt)
                acc[mt][nt] = __builtin_amdgcn_mfma_f32_16x16x32_bf16(
                    af[mt], bf[nt], acc[mt][nt], 0, 0, 0);
    }

    __syncthreads();   // all waves done reading tiles before part[] overwrites

    // fused epilogue: dist -> exp -> masked num/den, per (row, col-lane) partials
    float sqj_r[4]; int yj_r[4], jg[4];
    #pragma unroll
    for (int nt = 0; nt < 4; ++nt) {
        int jc = wn * 64 + nt * 16 + lr;
        sqj_r[nt] = sqj[jc]; yj_r[nt] = yj[jc]; jg[nt] = j0 + jc;
    }
    #pragma unroll
    for (int mt = 0; mt < 4; ++mt) {
        #pragma unroll
        for (int r = 0; r < 4; ++r) {
            int rloc = wm * 64 + mt * 16 + q * 4 + r;   // C/D: row = q*4+reg
            float si = sqi[rloc]; int yir = yi[rloc]; int ig = i0 + rloc;
            float n = 0.f, d = 0.f;
            #pragma unroll
            for (int nt = 0; nt < 4; ++nt) {
                float dist = fmaxf(si + sqj_r[nt] - 2.f * acc[mt][nt][r], 0.f);
                float e = __builtin_amdgcn_exp2f(dist * -0.014426950408889634f); // exp(-dist/100)
                d += e;
                bool ok = (yir == yj_r[nt]) && (ig != jg[nt]);
                n += ok ? e : 0.f;
            }
            *(float2*)&sm.part[((wn * 128 + rloc) * 17 + lr) * 2] = make_float2(n, d);
        }
    }
    __syncthreads();

    // per-block reduction: 2 threads per row sum 16 float2 each
    {
        int row = tid >> 1, h = tid & 1;
        const float2* p = (const float2*)&sm.part[(h * 128 + row) * 34];
        float sn = 0.f, sd = 0.f;
        #pragma unroll
        for (int c = 0; c < 16; ++c) { float2 v = p[c]; sn += v.x; sd += v.y; }
        sn += __shfl_down(sn, 1); sd += __shfl_down(sd, 1);
        if (h == 0) {
            atomicAdd(&num[i0 + row], sn);
            atomicAdd(&den[i0 + row], sd);
        }
    }
}

__global__ __launch_bounds__(256) void snn_final(const float* __restrict__ num,
        const float* __restrict__ den, float* __restrict__ out) {
    __shared__ float wsum[4];
    int i = blockIdx.x * 256 + threadIdx.x;
    float l = -__logf(num[i] / den[i]);
    #pragma unroll
    for (int off = 32; off > 0; off >>= 1) l += __shfl_down(l, off);
    int wid = threadIdx.x >> 6;
    if ((threadIdx.x & 63) == 0) wsum[wid] = l;
    __syncthreads();
    if (threadIdx.x == 0) {
        float s = wsum[0] + wsum[1] + wsum[2] + wsum[3];
        atomicAdd(out, s * (1.0f / NB));
    }
}

extern "C" void kernel_launch(void* const* d_in, const int* in_sizes, int n_in,
                              void* d_out, int out_size, void* d_ws, size_t ws_size,
                              hipStream_t stream) {
    const float* x = (const float*)d_in[0];
    const int*   y = (const int*)d_in[1];
    float* out = (float*)d_out;
    float* sq  = (float*)d_ws;
    float* num = sq + NB;
    float* den = num + NB;
    unsigned short* xb = (unsigned short*)(den + NB);

    prep_kernel<<<NB / 8, 256, 0, stream>>>(x, sq, num, den, out, xb);
    dim3 grid(NB / 128, NB / 128);
    snn_mfma<<<grid, 256, 0, stream>>>(xb, y, sq, num, den);
    snn_final<<<NB / 256, 256, 0, stream>>>(num, den, out);
}